// Round 1
// baseline (257.967 us; speedup 1.0000x reference)
//
#include <hip/hip_runtime.h>

// Problem constants (match reference: L=4, B=32, T=2048, D=100)
constexpr int kL = 4;
constexpr int kB = 32;
constexpr int kT = 2048;
constexpr int kD = 100;
constexpr int kCH = 16;              // t-chunks per (l,b)
constexpr int kTSUB = kT / kCH;      // 128 t per chunk
constexpr int kROWS = kL * kB * kD;  // 12800 softmax rows

// Pass 1: streaming partial sums per row (l,b,d):
//   S_p = sum_t exp(old_h), S_q = sum_t exp(h), W = sum_t exp(old_h)*(old_h - h)
// No max-subtraction: inputs are N(0,1) logits (|x| < ~6), exp cannot overflow fp32.
// Wave layout: ty = wave id (strides t), lanes dx<50 each own d = {2dx, 2dx+1} via
// float2 -> one 400-byte contiguous request per wave per t per array.
__global__ __launch_bounds__(256) void kl_partial(
    const float* __restrict__ h, const float* __restrict__ oh,
    float* __restrict__ wsp, float* __restrict__ wsq, float* __restrict__ ww) {
  const int lb = blockIdx.x / kCH;     // (l*B + b) in [0,128)
  const int chunk = blockIdx.x % kCH;  // t-chunk
  const int tid = threadIdx.x;
  const int ty = tid >> 6;             // wave id 0..3
  const int dx = tid & 63;             // lane
  const int d0 = dx * 2;
  const bool active = (dx < 50);

  const size_t base = ((size_t)lb * kT + (size_t)chunk * kTSUB) * kD;
  const float* __restrict__ hp = h + base;
  const float* __restrict__ op = oh + base;

  float sp0 = 0.f, sp1 = 0.f, sq0 = 0.f, sq1 = 0.f, w0 = 0.f, w1 = 0.f;
  if (active) {
    for (int t = ty; t < kTSUB; t += 4) {
      const size_t off = (size_t)t * kD + d0;  // 8B-aligned (even float offset)
      const float2 hv = *(const float2*)(hp + off);
      const float2 ov = *(const float2*)(op + off);
      const float ep0 = __expf(ov.x), ep1 = __expf(ov.y);
      const float eq0 = __expf(hv.x), eq1 = __expf(hv.y);
      sp0 += ep0; sp1 += ep1;
      sq0 += eq0; sq1 += eq1;
      w0 += ep0 * (ov.x - hv.x);
      w1 += ep1 * (ov.y - hv.y);
    }
  }

  // Reduce the 4 waves' partials in LDS, then one set of atomics per d.
  __shared__ float red[256][6];
  red[tid][0] = sp0; red[tid][1] = sp1;
  red[tid][2] = sq0; red[tid][3] = sq1;
  red[tid][4] = w0;  red[tid][5] = w1;
  __syncthreads();
  if (ty == 0 && active) {
    float a0 = 0.f, a1 = 0.f, a2 = 0.f, a3 = 0.f, a4 = 0.f, a5 = 0.f;
    #pragma unroll
    for (int g = 0; g < 4; ++g) {
      const float* r = red[g * 64 + dx];
      a0 += r[0]; a1 += r[1]; a2 += r[2]; a3 += r[3]; a4 += r[4]; a5 += r[5];
    }
    const int r = lb * kD + d0;
    atomicAdd(&wsp[r], a0);     atomicAdd(&wsp[r + 1], a1);
    atomicAdd(&wsq[r], a2);     atomicAdd(&wsq[r + 1], a3);
    atomicAdd(&ww[r], a4);      atomicAdd(&ww[r + 1], a5);
  }
}

// Pass 2 (single tiny block): softmax(layer_weights), softmax(class_weights),
// per-row KL = W/S_p - log(S_p) + log(S_q), weighted scalar reduce, /B.
__global__ __launch_bounds__(256) void kl_final(
    const float* __restrict__ wsp, const float* __restrict__ wsq,
    const float* __restrict__ ww, const float* __restrict__ lwin,
    const float* __restrict__ cwin, float* __restrict__ out) {
  __shared__ float lw[kL];
  __shared__ float cw[kD];
  __shared__ float red[256];
  const int tid = threadIdx.x;

  if (tid == 0) {  // softmax over 4 layer weights (serial: trivial)
    float m = lwin[0];
    for (int i = 1; i < kL; ++i) m = fmaxf(m, lwin[i]);
    float s = 0.f;
    for (int i = 0; i < kL; ++i) { const float e = __expf(lwin[i] - m); lw[i] = e; s += e; }
    const float inv = 1.0f / s;
    for (int i = 0; i < kL; ++i) lw[i] *= inv;
  }
  if (tid == 64) {  // softmax over 100 class weights (serial: trivial)
    float m = cwin[0];
    for (int i = 1; i < kD; ++i) m = fmaxf(m, cwin[i]);
    float s = 0.f;
    for (int i = 0; i < kD; ++i) { const float e = __expf(cwin[i] - m); cw[i] = e; s += e; }
    const float inv = 1.0f / s;
    for (int i = 0; i < kD; ++i) cw[i] *= inv;
  }
  __syncthreads();

  float acc = 0.f;
  for (int r = tid; r < kROWS; r += 256) {
    const int l = r / (kB * kD);
    const int d = r % kD;
    const float sp = wsp[r], sq = wsq[r], w = ww[r];
    const float val = w / sp - __logf(sp) + __logf(sq);
    acc += lw[l] * cw[d] * val;
  }
  red[tid] = acc;
  __syncthreads();
  for (int s = 128; s > 0; s >>= 1) {
    if (tid < s) red[tid] += red[tid + s];
    __syncthreads();
  }
  if (tid == 0) out[0] = red[0] / (float)kB;
}

extern "C" void kernel_launch(void* const* d_in, const int* in_sizes, int n_in,
                              void* d_out, int out_size, void* d_ws, size_t ws_size,
                              hipStream_t stream) {
  const float* h    = (const float*)d_in[0];  // [L,B,T,D] fp32
  const float* oh   = (const float*)d_in[1];  // [L,B,T,D] fp32
  const float* lwin = (const float*)d_in[2];  // [L] fp32
  const float* cwin = (const float*)d_in[3];  // [D] fp32

  float* wsp = (float*)d_ws;        // [kROWS] S_p
  float* wsq = wsp + kROWS;         // [kROWS] S_q
  float* ww  = wsq + kROWS;         // [kROWS] W
  // ws is re-poisoned to 0xAA before every launch -> zero the accumulators.
  hipMemsetAsync(d_ws, 0, (size_t)3 * kROWS * sizeof(float), stream);

  kl_partial<<<kL * kB * kCH, 256, 0, stream>>>(h, oh, wsp, wsq, ww);
  kl_final<<<1, 256, 0, stream>>>(wsp, wsq, ww, lwin, cwin, (float*)d_out);
}

// Round 2
// 243.099 us; speedup vs baseline: 1.0612x; 1.0612x over previous
//
#include <hip/hip_runtime.h>

// Problem constants (reference: L=4, B=32, T=2048, D=100)
constexpr int kL = 4;
constexpr int kB = 32;
constexpr int kT = 2048;
constexpr int kD = 100;
constexpr int kD4 = kD / 4;            // 25 float4 per row
constexpr int kCH = 16;                // t-chunks per (l,b) slab
constexpr int kTSUB = kT / kCH;        // 128 rows per chunk
constexpr int kROWS = kL * kB * kD;    // 12800 (l,b,d) softmax rows

// Pass 1: streaming partial sums per row (l,b,d) over a t-chunk:
//   S_p = sum_t exp(old_h), S_q = sum_t exp(h), W = sum_t exp(old_h)*(old_h-h)
// No max-subtraction: N(0,1) logits, exp cannot overflow fp32 (verified absmax=0 in R1).
// Lane map: half = lane/25 (row parity), d4 = lane%25 -> each wave loads TWO
// 400-B rows per issue as float4 (16 B/lane, 50/64 lanes active, 800 B/instr).
// Unroll 4 keeps 8 dwordx4 loads in flight per wave (~6.4 KB) to hide HBM latency.
__global__ __launch_bounds__(256) void kl_partial(
    const float4* __restrict__ h4, const float4* __restrict__ oh4,
    float* __restrict__ wsp, float* __restrict__ wsq, float* __restrict__ ww) {
  const int lb = blockIdx.x >> 4;      // (l*B+b) in [0,128)
  const int chunk = blockIdx.x & 15;
  const int tid = threadIdx.x;
  const int ty = tid >> 6;             // wave 0..3
  const int lane = tid & 63;
  const int half = lane / kD4;         // 0,1 active; 2 = idle lanes 50..63
  const int d4 = lane - half * kD4;    // float4 index within row
  const bool active = (lane < 2 * kD4);

  float4 sp = {0.f, 0.f, 0.f, 0.f};
  float4 sq = {0.f, 0.f, 0.f, 0.f};
  float4 w  = {0.f, 0.f, 0.f, 0.f};

  if (active) {
    const int row0 = chunk * kTSUB + ty * 2 + half;   // this lane's first row
    const size_t b4 = ((size_t)lb * kT + row0) * kD4 + d4;
    const float4* __restrict__ hp = h4 + b4;
    const float4* __restrict__ op = oh4 + b4;
#pragma unroll 4
    for (int i = 0; i < kTSUB / 8; ++i) {             // 16 iters, row stride 8
      const size_t off = (size_t)i * 8 * kD4;
      const float4 hv = hp[off];
      const float4 ov = op[off];
      const float ep0 = __expf(ov.x), ep1 = __expf(ov.y);
      const float ep2 = __expf(ov.z), ep3 = __expf(ov.w);
      sp.x += ep0; sp.y += ep1; sp.z += ep2; sp.w += ep3;
      sq.x += __expf(hv.x); sq.y += __expf(hv.y);
      sq.z += __expf(hv.z); sq.w += __expf(hv.w);
      w.x += ep0 * (ov.x - hv.x); w.y += ep1 * (ov.y - hv.y);
      w.z += ep2 * (ov.z - hv.z); w.w += ep3 * (ov.w - hv.w);
    }
  }

  // Block reduce: 8 contributors per d (4 waves x 2 row-halves), then 3 atomics/d.
  __shared__ float red[256][12];
  {
    float* r = red[tid];
    r[0] = sp.x; r[1] = sp.y; r[2]  = sp.z; r[3]  = sp.w;
    r[4] = sq.x; r[5] = sq.y; r[6]  = sq.z; r[7]  = sq.w;
    r[8] = w.x;  r[9] = w.y;  r[10] = w.z;  r[11] = w.w;
  }
  __syncthreads();
  if (tid < kD) {
    const int dd4 = tid >> 2, j = tid & 3;
    float asp = 0.f, asq = 0.f, aw = 0.f;
#pragma unroll
    for (int g = 0; g < 4; ++g) {
#pragma unroll
      for (int hh = 0; hh < 2; ++hh) {
        const float* s = red[g * 64 + hh * kD4 + dd4];
        asp += s[j]; asq += s[4 + j]; aw += s[8 + j];
      }
    }
    const int idx = lb * kD + tid;
    atomicAdd(&wsp[idx], asp);
    atomicAdd(&wsq[idx], asq);
    atomicAdd(&ww[idx],  aw);
  }
}

// Pass 2: 50 blocks x 256 threads, one thread per (l,b,d) row.
// val = W/S_p - log(S_p) + log(S_q); weighted by softmax(lw)[l]*softmax(cw)[d];
// block-reduce then one atomicAdd into ws scalar.
__global__ __launch_bounds__(256) void kl_reduce(
    const float* __restrict__ wsp, const float* __restrict__ wsq,
    const float* __restrict__ ww, const float* __restrict__ lwin,
    const float* __restrict__ cwin, float* __restrict__ acc) {
  __shared__ float lw[kL];
  __shared__ float cw[kD];
  __shared__ float sred[256];
  const int tid = threadIdx.x;

  if (tid == 0) {
    float m = lwin[0];
    for (int i = 1; i < kL; ++i) m = fmaxf(m, lwin[i]);
    float e[kL], s = 0.f;
    for (int i = 0; i < kL; ++i) { e[i] = __expf(lwin[i] - m); s += e[i]; }
    const float inv = 1.0f / s;
    for (int i = 0; i < kL; ++i) lw[i] = e[i] * inv;
  }
  if (tid == 64) {
    float m = cwin[0];
    for (int i = 1; i < kD; ++i) m = fmaxf(m, cwin[i]);
    float s = 0.f;
    for (int i = 0; i < kD; ++i) { const float e = __expf(cwin[i] - m); cw[i] = e; s += e; }
    const float inv = 1.0f / s;
    for (int i = 0; i < kD; ++i) cw[i] *= inv;
  }
  __syncthreads();

  const int r = blockIdx.x * 256 + tid;          // < 12800 (grid = 50)
  const int l = r / (kB * kD);
  const int d = r % kD;
  const float spv = wsp[r], sqv = wsq[r], wv = ww[r];
  const float val = wv / spv - __logf(spv) + __logf(sqv);
  sred[tid] = lw[l] * cw[d] * val;
  __syncthreads();
  for (int s = 128; s > 0; s >>= 1) {
    if (tid < s) sred[tid] += sred[tid + s];
    __syncthreads();
  }
  if (tid == 0) atomicAdd(acc, sred[0]);
}

__global__ void kl_write(const float* __restrict__ acc, float* __restrict__ out) {
  out[0] = acc[0] / (float)kB;
}

extern "C" void kernel_launch(void* const* d_in, const int* in_sizes, int n_in,
                              void* d_out, int out_size, void* d_ws, size_t ws_size,
                              hipStream_t stream) {
  const float* h    = (const float*)d_in[0];  // [L,B,T,D] fp32
  const float* oh   = (const float*)d_in[1];  // [L,B,T,D] fp32
  const float* lwin = (const float*)d_in[2];  // [L] fp32
  const float* cwin = (const float*)d_in[3];  // [D] fp32

  float* wsp = (float*)d_ws;        // [kROWS] S_p
  float* wsq = wsp + kROWS;         // [kROWS] S_q
  float* ww  = wsq + kROWS;         // [kROWS] W
  float* acc = ww + kROWS;          // [1] weighted scalar accumulator
  // ws is re-poisoned to 0xAA before every launch -> zero accumulators + acc.
  hipMemsetAsync(d_ws, 0, ((size_t)3 * kROWS + 1) * sizeof(float), stream);

  kl_partial<<<kL * kB * kCH, 256, 0, stream>>>(
      (const float4*)h, (const float4*)oh, wsp, wsq, ww);
  kl_reduce<<<kROWS / 256, 256, 0, stream>>>(wsp, wsq, ww, lwin, cwin, acc);
  kl_write<<<1, 1, 0, stream>>>(acc, (float*)d_out);
}

// Round 3
// 239.067 us; speedup vs baseline: 1.0791x; 1.0169x over previous
//
#include <hip/hip_runtime.h>

// Problem constants (reference: L=4, B=32, T=2048, D=100)
constexpr int kL = 4;
constexpr int kB = 32;
constexpr int kT = 2048;
constexpr int kD = 100;
constexpr int kD4 = kD / 4;            // 25 float4 per row
constexpr int kCH = 16;                // t-chunks per (l,b) slab
constexpr int kTSUB = kT / kCH;        // 128 rows per chunk
constexpr int kROWS = kL * kB * kD;    // 12800 (l,b,d) softmax rows

// Pass 1: streaming partial sums per row (l,b,d) over a t-chunk:
//   S_p = sum_t exp(old_h), S_q = sum_t exp(h), W = sum_t exp(old_h)*(old_h-h)
// No max-subtraction: N(0,1) logits, exp cannot overflow fp32 (absmax=0 in R1/R2).
//
// Lane map: half = lane/25, d4 = lane%25 -> each wave covers TWO contiguous
// 400-B rows per load (50/64 lanes, 800 B contiguous per instruction).
// MLP fix (R3): batch FOUR row-pair passes per iteration into 8 separately
// named float4 locals, all loaded before any compute -> 8 independent
// global_load_dwordx4 in flight per wave (6.4 KB). R2's version collapsed to
// ~2 in flight (VGPR=40); this one needs ~56-72 VGPRs -- verify in counters.
__global__ __launch_bounds__(256) void kl_partial(
    const float4* __restrict__ h4, const float4* __restrict__ oh4,
    float* __restrict__ wsp, float* __restrict__ wsq, float* __restrict__ ww) {
  const int lb = blockIdx.x >> 4;      // (l*B+b) in [0,128)
  const int chunk = blockIdx.x & 15;
  const int tid = threadIdx.x;
  const int ty = tid >> 6;             // wave 0..3
  const int lane = tid & 63;
  const int half = lane / kD4;         // 0,1 active; lanes 50..63 idle
  const int d4 = lane - half * kD4;
  const bool active = (lane < 2 * kD4);

  float4 sp = {0.f, 0.f, 0.f, 0.f};
  float4 sq = {0.f, 0.f, 0.f, 0.f};
  float4 w  = {0.f, 0.f, 0.f, 0.f};

  if (active) {
    // Pass p (p=0..15) covers rows p*8 + ty*2 + half; iteration i batches
    // passes 4i..4i+3 -> float4 offsets i*800 + {0,200,400,600}.
    const int row0 = chunk * kTSUB + ty * 2 + half;
    const size_t b4 = ((size_t)lb * kT + row0) * kD4 + d4;
    const float4* __restrict__ hp = h4 + b4;
    const float4* __restrict__ op = oh4 + b4;
    for (int i = 0; i < 4; ++i) {
      // --- 8 independent loads, no compute between them ---
      const float4 h0 = hp[0];
      const float4 o0 = op[0];
      const float4 h1 = hp[200];
      const float4 o1 = op[200];
      const float4 h2 = hp[400];
      const float4 o2 = op[400];
      const float4 h3 = hp[600];
      const float4 o3 = op[600];
      hp += 800; op += 800;
      // --- consume ---
      {
        const float a = __expf(o0.x), b = __expf(o0.y), c = __expf(o0.z), d = __expf(o0.w);
        sp.x += a; sp.y += b; sp.z += c; sp.w += d;
        sq.x += __expf(h0.x); sq.y += __expf(h0.y); sq.z += __expf(h0.z); sq.w += __expf(h0.w);
        w.x += a * (o0.x - h0.x); w.y += b * (o0.y - h0.y);
        w.z += c * (o0.z - h0.z); w.w += d * (o0.w - h0.w);
      }
      {
        const float a = __expf(o1.x), b = __expf(o1.y), c = __expf(o1.z), d = __expf(o1.w);
        sp.x += a; sp.y += b; sp.z += c; sp.w += d;
        sq.x += __expf(h1.x); sq.y += __expf(h1.y); sq.z += __expf(h1.z); sq.w += __expf(h1.w);
        w.x += a * (o1.x - h1.x); w.y += b * (o1.y - h1.y);
        w.z += c * (o1.z - h1.z); w.w += d * (o1.w - h1.w);
      }
      {
        const float a = __expf(o2.x), b = __expf(o2.y), c = __expf(o2.z), d = __expf(o2.w);
        sp.x += a; sp.y += b; sp.z += c; sp.w += d;
        sq.x += __expf(h2.x); sq.y += __expf(h2.y); sq.z += __expf(h2.z); sq.w += __expf(h2.w);
        w.x += a * (o2.x - h2.x); w.y += b * (o2.y - h2.y);
        w.z += c * (o2.z - h2.z); w.w += d * (o2.w - h2.w);
      }
      {
        const float a = __expf(o3.x), b = __expf(o3.y), c = __expf(o3.z), d = __expf(o3.w);
        sp.x += a; sp.y += b; sp.z += c; sp.w += d;
        sq.x += __expf(h3.x); sq.y += __expf(h3.y); sq.z += __expf(h3.z); sq.w += __expf(h3.w);
        w.x += a * (o3.x - h3.x); w.y += b * (o3.y - h3.y);
        w.z += c * (o3.z - h3.z); w.w += d * (o3.w - h3.w);
      }
    }
  }

  // Block reduce: 8 contributors per d (4 waves x 2 row-halves), then 3 atomics/d.
  __shared__ float red[256][12];
  {
    float* r = red[tid];
    r[0] = sp.x; r[1] = sp.y; r[2]  = sp.z; r[3]  = sp.w;
    r[4] = sq.x; r[5] = sq.y; r[6]  = sq.z; r[7]  = sq.w;
    r[8] = w.x;  r[9] = w.y;  r[10] = w.z;  r[11] = w.w;
  }
  __syncthreads();
  if (tid < kD) {
    const int dd4 = tid >> 2, j = tid & 3;
    float asp = 0.f, asq = 0.f, aw = 0.f;
#pragma unroll
    for (int g = 0; g < 4; ++g) {
#pragma unroll
      for (int hh = 0; hh < 2; ++hh) {
        const float* s = red[g * 64 + hh * kD4 + dd4];
        asp += s[j]; asq += s[4 + j]; aw += s[8 + j];
      }
    }
    const int idx = lb * kD + tid;
    atomicAdd(&wsp[idx], asp);
    atomicAdd(&wsq[idx], asq);
    atomicAdd(&ww[idx],  aw);
  }
}

// Pass 2: 50 blocks x 256 threads, one thread per (l,b,d) row.
__global__ __launch_bounds__(256) void kl_reduce(
    const float* __restrict__ wsp, const float* __restrict__ wsq,
    const float* __restrict__ ww, const float* __restrict__ lwin,
    const float* __restrict__ cwin, float* __restrict__ acc) {
  __shared__ float lw[kL];
  __shared__ float cw[kD];
  __shared__ float sred[256];
  const int tid = threadIdx.x;

  if (tid == 0) {
    float m = lwin[0];
    for (int i = 1; i < kL; ++i) m = fmaxf(m, lwin[i]);
    float e[kL], s = 0.f;
    for (int i = 0; i < kL; ++i) { e[i] = __expf(lwin[i] - m); s += e[i]; }
    const float inv = 1.0f / s;
    for (int i = 0; i < kL; ++i) lw[i] = e[i] * inv;
  }
  if (tid == 64) {
    float m = cwin[0];
    for (int i = 1; i < kD; ++i) m = fmaxf(m, cwin[i]);
    float s = 0.f;
    for (int i = 0; i < kD; ++i) { const float e = __expf(cwin[i] - m); cw[i] = e; s += e; }
    const float inv = 1.0f / s;
    for (int i = 0; i < kD; ++i) cw[i] *= inv;
  }
  __syncthreads();

  const int r = blockIdx.x * 256 + tid;          // < 12800 (grid = 50)
  const int l = r / (kB * kD);
  const int d = r % kD;
  const float spv = wsp[r], sqv = wsq[r], wv = ww[r];
  const float val = wv / spv - __logf(spv) + __logf(sqv);
  sred[tid] = lw[l] * cw[d] * val;
  __syncthreads();
  for (int s = 128; s > 0; s >>= 1) {
    if (tid < s) sred[tid] += sred[tid + s];
    __syncthreads();
  }
  if (tid == 0) atomicAdd(acc, sred[0]);
}

__global__ void kl_write(const float* __restrict__ acc, float* __restrict__ out) {
  out[0] = acc[0] / (float)kB;
}

extern "C" void kernel_launch(void* const* d_in, const int* in_sizes, int n_in,
                              void* d_out, int out_size, void* d_ws, size_t ws_size,
                              hipStream_t stream) {
  const float* h    = (const float*)d_in[0];  // [L,B,T,D] fp32
  const float* oh   = (const float*)d_in[1];  // [L,B,T,D] fp32
  const float* lwin = (const float*)d_in[2];  // [L] fp32
  const float* cwin = (const float*)d_in[3];  // [D] fp32

  float* wsp = (float*)d_ws;        // [kROWS] S_p
  float* wsq = wsp + kROWS;         // [kROWS] S_q
  float* ww  = wsq + kROWS;         // [kROWS] W
  float* acc = ww + kROWS;          // [1] weighted scalar accumulator
  // ws is re-poisoned to 0xAA before every launch -> zero accumulators + acc.
  hipMemsetAsync(d_ws, 0, ((size_t)3 * kROWS + 1) * sizeof(float), stream);

  kl_partial<<<kL * kB * kCH, 256, 0, stream>>>(
      (const float4*)h, (const float4*)oh, wsp, wsq, ww);
  kl_reduce<<<kROWS / 256, 256, 0, stream>>>(wsp, wsq, ww, lwin, cwin, acc);
  kl_write<<<1, 1, 0, stream>>>(acc, (float*)d_out);
}